// Round 21
// baseline (132.475 us; speedup 1.0000x reference)
//
#include <hip/hip_runtime.h>
#include <hip/hip_bf16.h>
#include <math.h>

// GCN 2-layer forward, round-21: exact r16 pipeline (best: 128.06us) with the
// gemm1 half of k_cnt_gemm1 rebuilt: 32-node tiles / 512-thread blocks, float4
// LDS reads, 4 independent K-chunk accumulators (dep chain 128 -> 32 FMAs).
// Everything else byte-identical to r16. Assumes N <= 131072.

#define F_IN 128
#define H1 16
#define C_OUT 2
#define SBS 1024         // nodes per super-bucket
#define LOG_SBS 10
#define NSB_MAX 128
#define SRC_MASK 0x3FFFFF   // 22-bit src
#define CH1 4096         // edges per chunk (782 chunks)
#define SLICE 128        // nodes per place-slice
#define NSLICE (SBS / SLICE)   // 8
#define PCAP 5632        // staged edges per slice (expected ~4096, +24 sigma)

typedef int ix4 __attribute__((ext_vector_type(4)));

__device__ __forceinline__ float bflo(unsigned u) { return __uint_as_float(u << 16); }
__device__ __forceinline__ float bfhi(unsigned u) { return __uint_as_float(u & 0xFFFF0000u); }

// ---- fused: [0, nblk) = per-chunk SB histogram (256 active thr);
//      [nblk, ..) = layer-1 GEMM, 32 nodes per 512-thread block ----
__global__ __launch_bounds__(512) void k_cnt_gemm1(
    const int* __restrict__ dst0, int* __restrict__ cntm,
    const float* __restrict__ x, const float* __restrict__ W1,
    __hip_bfloat16* __restrict__ h1b,
    int E, int NSB, int nblk, int N) {
    __shared__ int sc[NSB_MAX];
    __shared__ float w[F_IN * H1];     // 8 KB
    __shared__ float xt[32 * F_IN];    // 16 KB
    int t = threadIdx.x;
    if (blockIdx.x < (unsigned)nblk) {
        // ---- cnt (use 256 threads; rest idle through barriers) ----
        if (t < NSB_MAX) sc[t] = 0;
        __syncthreads();
        int e0 = blockIdx.x * CH1, e1 = min(e0 + CH1, E);
        int n4 = (e1 - e0) >> 2;
        const ix4* d4 = (const ix4*)(dst0 + e0);
        for (int i = t; i < n4; i += 512) {
            ix4 d = __builtin_nontemporal_load(&d4[i]);
            atomicAdd(&sc[((unsigned)d.x) >> LOG_SBS], 1);
            atomicAdd(&sc[((unsigned)d.y) >> LOG_SBS], 1);
            atomicAdd(&sc[((unsigned)d.z) >> LOG_SBS], 1);
            atomicAdd(&sc[((unsigned)d.w) >> LOG_SBS], 1);
        }
        for (int e = e0 + n4 * 4 + t; e < e1; e += 512)
            atomicAdd(&sc[((unsigned)dst0[e]) >> LOG_SBS], 1);
        __syncthreads();
        for (int b = t; b < NSB; b += 512)
            cntm[(size_t)b * nblk + blockIdx.x] = sc[b];
    } else {
        // ---- gemm1 (UNSCALED h1): 32 nodes, 512 threads ----
        int node0 = (blockIdx.x - nblk) * 32;
        const float4* W14 = (const float4*)W1;
        float4* w4 = (float4*)w;
        for (int i = t; i < F_IN * H1 / 4; i += 512) w4[i] = W14[i];
        const float4* x4 = (const float4*)x;
        float4* xt4 = (float4*)xt;
        for (int i = t; i < 32 * F_IN / 4; i += 512) {
            int r = i >> 5;
            int node = node0 + r;
            xt4[i] = (node < N) ? x4[(size_t)node * 32 + (i & 31)]
                                : make_float4(0.f, 0.f, 0.f, 0.f);
        }
        __syncthreads();
        int nsub = t >> 4, f = t & 15;          // 32 nodes x 16 feats
        int node = node0 + nsub;
        if (node < N) {
            const float4* xr = (const float4*)(xt + nsub * F_IN);
            // 4 independent K-chunk accumulators, float4 LDS reads
            float a0 = 0.f, a1 = 0.f, a2 = 0.f, a3 = 0.f;
            #pragma unroll
            for (int k4 = 0; k4 < 8; ++k4) {     // 8 float4 per chunk of 32
                float4 v0 = xr[k4];
                float4 v1 = xr[8 + k4];
                float4 v2 = xr[16 + k4];
                float4 v3 = xr[24 + k4];
                int k0 = k4 * 4;
                a0 = fmaf(v0.x, w[(k0+0)*H1+f], a0);
                a0 = fmaf(v0.y, w[(k0+1)*H1+f], a0);
                a0 = fmaf(v0.z, w[(k0+2)*H1+f], a0);
                a0 = fmaf(v0.w, w[(k0+3)*H1+f], a0);
                a1 = fmaf(v1.x, w[(32+k0+0)*H1+f], a1);
                a1 = fmaf(v1.y, w[(32+k0+1)*H1+f], a1);
                a1 = fmaf(v1.z, w[(32+k0+2)*H1+f], a1);
                a1 = fmaf(v1.w, w[(32+k0+3)*H1+f], a1);
                a2 = fmaf(v2.x, w[(64+k0+0)*H1+f], a2);
                a2 = fmaf(v2.y, w[(64+k0+1)*H1+f], a2);
                a2 = fmaf(v2.z, w[(64+k0+2)*H1+f], a2);
                a2 = fmaf(v2.w, w[(64+k0+3)*H1+f], a2);
                a3 = fmaf(v3.x, w[(96+k0+0)*H1+f], a3);
                a3 = fmaf(v3.y, w[(96+k0+1)*H1+f], a3);
                a3 = fmaf(v3.z, w[(96+k0+2)*H1+f], a3);
                a3 = fmaf(v3.w, w[(96+k0+3)*H1+f], a3);
            }
            h1b[(size_t)node * H1 + f] = __float2bfloat16((a0 + a1) + (a2 + a3));
        }
    }
}

// ---- pass 0b: per-SB exclusive scan over chunks (block per SB) + totals ----
__global__ __launch_bounds__(1024) void k_cscan(
    int* __restrict__ cntm, int* __restrict__ tot, int* __restrict__ rp,
    int NSB, int nblk, int E) {
    __shared__ int s[1024];
    int b = blockIdx.x, t = threadIdx.x;
    int* row = cntm + (size_t)b * nblk;
    int own = (t < nblk) ? row[t] : 0;
    s[t] = own;
    __syncthreads();
    for (int off = 1; off < 1024; off <<= 1) {
        int v = (t >= off) ? s[t - off] : 0;
        __syncthreads();
        s[t] += v;
        __syncthreads();
    }
    if (t < nblk) row[t] = s[t] - own;      // exclusive prefix
    if (t == 0) tot[b] = s[1023];           // SB total (zero-padded tail)
    if (b == 0 && t == 0) rp[NSB * SBS] = E;
}

// ---- pass 1: scatter (src | dst_local<<22) at precomputed offsets ----
__global__ __launch_bounds__(512) void k_scat1(
    const int* __restrict__ src0, const int* __restrict__ dst0,
    const int* __restrict__ cntm, unsigned* __restrict__ packed1,
    int E, int NSB, int nblk, int CAP) {
    __shared__ int lcur[NSB_MAX];
    int t = threadIdx.x, blk = blockIdx.x;
    for (int b = t; b < NSB; b += 512)
        lcur[b] = b * CAP + cntm[(size_t)b * nblk + blk];
    __syncthreads();
    int e0 = blk * CH1, e1 = min(e0 + CH1, E);
    int n4 = (e1 - e0) >> 2;
    const ix4* d4 = (const ix4*)(dst0 + e0);
    const ix4* s4 = (const ix4*)(src0 + e0);
    for (int i = t; i < n4; i += 512) {
        ix4 d = __builtin_nontemporal_load(&d4[i]);
        ix4 s = __builtin_nontemporal_load(&s4[i]);
        {
            unsigned dd = (unsigned)d.x;
            int pos = atomicAdd(&lcur[dd >> LOG_SBS], 1);
            packed1[pos] = (unsigned)s.x | ((dd & (SBS - 1)) << 22);
        }
        {
            unsigned dd = (unsigned)d.y;
            int pos = atomicAdd(&lcur[dd >> LOG_SBS], 1);
            packed1[pos] = (unsigned)s.y | ((dd & (SBS - 1)) << 22);
        }
        {
            unsigned dd = (unsigned)d.z;
            int pos = atomicAdd(&lcur[dd >> LOG_SBS], 1);
            packed1[pos] = (unsigned)s.z | ((dd & (SBS - 1)) << 22);
        }
        {
            unsigned dd = (unsigned)d.w;
            int pos = atomicAdd(&lcur[dd >> LOG_SBS], 1);
            packed1[pos] = (unsigned)s.w | ((dd & (SBS - 1)) << 22);
        }
    }
    for (int e = e0 + n4 * 4 + t; e < e1; e += 512) {
        unsigned dd = (unsigned)dst0[e];
        int pos = atomicAdd(&lcur[dd >> LOG_SBS], 1);
        packed1[pos] = (unsigned)src0[e] | ((dd & (SBS - 1)) << 22);
    }
}

// ---- pass 2a: per-SB histogram + scan -> rp, dinv; epilogue: h1b *= dinv ----
__global__ __launch_bounds__(1024) void k_hist(
    const unsigned* __restrict__ packed1, const int* __restrict__ tot,
    int* __restrict__ rp, float* __restrict__ dinv,
    __hip_bfloat16* __restrict__ h1b, int N, int NSB, int CAP) {
    __shared__ int cnt[SBS];
    __shared__ int s2[SBS];
    __shared__ int sbase[NSB_MAX];
    int b = blockIdx.x, t = threadIdx.x;
    if (t < NSB_MAX) sbase[t] = (t < NSB) ? tot[t] : 0;
    cnt[t] = 0;
    __syncthreads();
    if (t == 0) {
        int run = 0;
        #pragma unroll 4
        for (int i = 0; i < NSB_MAX; ++i) { int c = sbase[i]; sbase[i] = run; run += c; }
    }
    __syncthreads();
    int cntb = tot[b];
    int e0 = b * CAP, e1 = e0 + cntb;
    int obase = sbase[b];
    int n4 = cntb >> 2;
    const ix4* p4 = (const ix4*)(packed1 + e0);
    for (int i = t; i < n4; i += 1024) {
        ix4 p = p4[i];
        atomicAdd(&cnt[((unsigned)p.x) >> 22], 1);
        atomicAdd(&cnt[((unsigned)p.y) >> 22], 1);
        atomicAdd(&cnt[((unsigned)p.z) >> 22], 1);
        atomicAdd(&cnt[((unsigned)p.w) >> 22], 1);
    }
    for (int e = e0 + n4 * 4 + t; e < e1; e += 1024)
        atomicAdd(&cnt[packed1[e] >> 22], 1);
    __syncthreads();
    int c = cnt[t];
    s2[t] = c;
    __syncthreads();
    for (int off = 1; off < 1024; off <<= 1) {
        int v = (t >= off) ? s2[t - off] : 0;
        __syncthreads();
        s2[t] += v;
        __syncthreads();
    }
    int ep = s2[t] - c;                 // exclusive prefix within SB
    int node = (b << LOG_SBS) + t;
    rp[node] = obase + ep;              // defined for ALL SB nodes
    if (node < N) {
        float dv = rsqrtf((float)(c + 1));   // +1 self-loop
        dinv[node] = dv;
        uint4* hrow = (uint4*)(h1b + (size_t)node * H1);
        uint4 s0 = hrow[0], s1 = hrow[1];
        unsigned r0[8];
        float v0, v1;
        #define SCALE_PACK(word, outi) \
            v0 = bflo(word) * dv; v1 = bfhi(word) * dv; \
            r0[outi] = (unsigned)__bfloat16_as_ushort(__float2bfloat16(v0)) | \
                       ((unsigned)__bfloat16_as_ushort(__float2bfloat16(v1)) << 16);
        SCALE_PACK(s0.x, 0) SCALE_PACK(s0.y, 1) SCALE_PACK(s0.z, 2) SCALE_PACK(s0.w, 3)
        SCALE_PACK(s1.x, 4) SCALE_PACK(s1.y, 5) SCALE_PACK(s1.z, 6) SCALE_PACK(s1.w, 7)
        #undef SCALE_PACK
        hrow[0] = make_uint4(r0[0], r0[1], r0[2], r0[3]);
        hrow[1] = make_uint4(r0[4], r0[5], r0[6], r0[7]);
    }
}

// ---- pass 2b+agg1: placement + in-block layer-1 aggregation ----
__global__ __launch_bounds__(512) void k_place_agg1(
    const unsigned* __restrict__ packed1, const int* __restrict__ tot,
    const int* __restrict__ rp, int* __restrict__ packed2,
    const __hip_bfloat16* __restrict__ h1b, const float* __restrict__ dinv,
    const float* __restrict__ b1, const float* __restrict__ W2,
    float* __restrict__ h2s,
    int N, int NSB, int PADB, int CAP) {
    __shared__ int cur[SLICE];
    __shared__ int lbuf[PCAP];
    int bid = blockIdx.x;
    int s = bid / PADB, b = bid - s * PADB;
    if (b >= NSB) return;
    int t = threadIdx.x;
    int node0 = (b << LOG_SBS) + s * SLICE;
    int g0 = rp[node0];
    if (t < SLICE) cur[t] = rp[node0 + t] - g0;
    int slice_len = rp[node0 + SLICE] - g0;
    __syncthreads();
    int cntb = tot[b];
    int e0 = b * CAP, e1 = e0 + cntb;
    int n4 = cntb >> 2;
    const ix4* p4 = (const ix4*)(packed1 + e0);
    for (int i = t; i < n4; i += 512) {
        ix4 p = p4[i];
        {
            unsigned nd = ((unsigned)p.x) >> 22;
            if ((nd >> 7) == (unsigned)s) {
                int pos = atomicAdd(&cur[nd & (SLICE - 1)], 1);
                if (pos < PCAP) lbuf[pos] = p.x & SRC_MASK;
            }
        }
        {
            unsigned nd = ((unsigned)p.y) >> 22;
            if ((nd >> 7) == (unsigned)s) {
                int pos = atomicAdd(&cur[nd & (SLICE - 1)], 1);
                if (pos < PCAP) lbuf[pos] = p.y & SRC_MASK;
            }
        }
        {
            unsigned nd = ((unsigned)p.z) >> 22;
            if ((nd >> 7) == (unsigned)s) {
                int pos = atomicAdd(&cur[nd & (SLICE - 1)], 1);
                if (pos < PCAP) lbuf[pos] = p.z & SRC_MASK;
            }
        }
        {
            unsigned nd = ((unsigned)p.w) >> 22;
            if ((nd >> 7) == (unsigned)s) {
                int pos = atomicAdd(&cur[nd & (SLICE - 1)], 1);
                if (pos < PCAP) lbuf[pos] = p.w & SRC_MASK;
            }
        }
    }
    for (int e = e0 + n4 * 4 + t; e < e1; e += 512) {
        unsigned p = packed1[e];
        unsigned nd = p >> 22;
        if ((nd >> 7) == (unsigned)s) {
            int pos = atomicAdd(&cur[nd & (SLICE - 1)], 1);
            if (pos < PCAP) lbuf[pos] = (int)(p & SRC_MASK);
        }
    }
    __syncthreads();
    // write packed2 for agg2 (sequential full-line writes)
    int lim = min(slice_len, PCAP);
    for (int i = t; i < lim; i += 512)
        packed2[g0 + i] = lbuf[i];
    // ---- fused layer-1 aggregation: 4 threads/node from LDS indices ----
    int g = t >> 2, q = t & 3;          // g in [0,128)
    int node = node0 + g;
    if (node < N) {
        const uint2* hv = (const uint2*)h1b;   // 8B chunks; row = 4 chunks
        float a[4];
        uint2 sv = hv[(size_t)node * 4 + q];   // self (pre-scaled)
        a[0] = bflo(sv.x); a[1] = bfhi(sv.x); a[2] = bflo(sv.y); a[3] = bfhi(sv.y);
        int lb = rp[node] - g0;
        int le = min(rp[node + 1] - g0, PCAP);
        for (; lb + 8 <= le; lb += 8) {
            int p[8];
            #pragma unroll
            for (int u = 0; u < 8; ++u) p[u] = lbuf[lb + u];
            uint2 v[8];
            #pragma unroll
            for (int u = 0; u < 8; ++u) v[u] = hv[(size_t)p[u] * 4 + q];
            #pragma unroll
            for (int u = 0; u < 8; ++u) {
                a[0] += bflo(v[u].x); a[1] += bfhi(v[u].x);
                a[2] += bflo(v[u].y); a[3] += bfhi(v[u].y);
            }
        }
        for (; lb < le; ++lb) {
            uint2 v = hv[(size_t)lbuf[lb] * 4 + q];
            a[0] += bflo(v.x); a[1] += bfhi(v.x); a[2] += bflo(v.y); a[3] += bfhi(v.y);
        }
        float dv = dinv[node];
        float c0 = 0.f, c1 = 0.f;
        #pragma unroll
        for (int j = 0; j < 4; ++j) {
            int f = q * 4 + j;
            float vv = fmaxf(fmaf(a[j], dv, b1[f]), 0.f);
            c0 = fmaf(vv, W2[f * C_OUT + 0], c0);
            c1 = fmaf(vv, W2[f * C_OUT + 1], c1);
        }
        c0 += __shfl_xor(c0, 1);
        c1 += __shfl_xor(c1, 1);
        c0 += __shfl_xor(c0, 2);
        c1 += __shfl_xor(c1, 2);
        if (q == 0)
            ((float2*)h2s)[node] = make_float2(c0 * dv, c1 * dv);
    }
}

// ---- layer 2 aggregate + log_softmax, 2 threads per node ----
__global__ __launch_bounds__(256) void k_agg2(
    const int* __restrict__ packed2, const int* __restrict__ rp,
    const float* __restrict__ h2s, const float* __restrict__ dinv,
    const float* __restrict__ b2, float* __restrict__ out, int N) {
    int tid = blockIdx.x * 256 + threadIdx.x;
    int n = tid >> 1, q = tid & 1;
    if (n >= N) return;
    float a = h2s[2 * (size_t)n + q];   // self-loop
    int e = rp[n], e1 = rp[n + 1];
    for (; e + 8 <= e1; e += 8) {
        int p[8];
        #pragma unroll
        for (int u = 0; u < 8; ++u) p[u] = packed2[e + u];
        float v[8];
        #pragma unroll
        for (int u = 0; u < 8; ++u) v[u] = h2s[2 * (size_t)p[u] + q];
        #pragma unroll
        for (int u = 0; u < 8; ++u) a += v[u];
    }
    for (; e < e1; ++e) a += h2s[2 * (size_t)packed2[e] + q];
    float dv = dinv[n];
    a = fmaf(a, dv, b2[q]);
    float other = __shfl_xor(a, 1);
    if (q == 0) {
        float a0 = a, a1 = other;
        float m = fmaxf(a0, a1);
        float lse = m + logf(expf(a0 - m) + expf(a1 - m));
        ((float2*)out)[n] = make_float2(a0 - lse, a1 - lse);
    }
}

extern "C" void kernel_launch(void* const* d_in, const int* in_sizes, int n_in,
                              void* d_out, int out_size, void* d_ws, size_t ws_size,
                              hipStream_t stream) {
    const float* x  = (const float*)d_in[0];
    const int* ei   = (const int*)d_in[1];
    const float* W1 = (const float*)d_in[2];
    const float* b1 = (const float*)d_in[3];
    const float* W2 = (const float*)d_in[4];
    const float* b2 = (const float*)d_in[5];
    float* out = (float*)d_out;

    const int N = in_sizes[0] / F_IN;     // 100000 (assumed <= 131072)
    const int E = in_sizes[1] / 2;        // 3200000
    const int* src0 = ei;
    const int* dst0 = ei + E;

    const int NSB = (N + SBS - 1) >> LOG_SBS;    // 98
    const int nblk = (E + CH1 - 1) / CH1;        // 782 (must be <= 1024 for cscan)
    const int PADB = (NSB + 7) & ~7;             // 104 (x8 XCD-stable mapping)
    int expSB = (int)(((long long)E << LOG_SBS) / N);
    int CAP = (expSB + expSB / 8 + 2048 + 15) & ~15;

    // workspace layout (float units), 16B-aligned chunks
    size_t off = 0;
    float* wsf = (float*)d_ws;
    auto take = [&](size_t nf) { float* p = wsf + off; off += (nf + 3) & ~(size_t)3; return p; };
    float* dinv    = take(N);
    __hip_bfloat16* h1b = (__hip_bfloat16*)take((size_t)N * H1 / 2);
    float* h2s     = take((size_t)N * C_OUT);
    unsigned* packed1 = (unsigned*)take((size_t)NSB * CAP);
    int*   packed2 = (int*)take(E);
    int*   cntm    = (int*)take((size_t)NSB * nblk);
    int*   tot     = (int*)take(NSB_MAX);
    int*   rp      = (int*)take((size_t)NSB * SBS + 1);

    int nbGemm = (N + 31) / 32;
    k_cnt_gemm1<<<nblk + nbGemm, 512, 0, stream>>>(dst0, cntm, x, W1, h1b, E, NSB, nblk, N);
    k_cscan<<<NSB, 1024, 0, stream>>>(cntm, tot, rp, NSB, nblk, E);
    k_scat1<<<nblk, 512, 0, stream>>>(src0, dst0, cntm, packed1, E, NSB, nblk, CAP);
    k_hist<<<NSB, 1024, 0, stream>>>(packed1, tot, rp, dinv, h1b, N, NSB, CAP);
    k_place_agg1<<<NSLICE * PADB, 512, 0, stream>>>(packed1, tot, rp, packed2,
                                                    h1b, dinv, b1, W2, h2s, N, NSB, PADB, CAP);
    k_agg2<<<(2 * N + 255) / 256, 256, 0, stream>>>(packed2, rp, h2s, dinv, b2, out, N);
}

// Round 22
// 124.615 us; speedup vs baseline: 1.0631x; 1.0631x over previous
//
#include <hip/hip_runtime.h>
#include <hip/hip_bf16.h>
#include <math.h>

// GCN 2-layer forward, round-22: r21 with the gemm1 LDS tile PADDED:
// xt row stride 128 -> 132 floats (33 float4), so the 4 nodes per wave hit
// disjoint bank groups (132 % 32 = 4) -> conflict-free float4 reads.
// r21 evidence: 5.0M SQ_LDS_BANK_CONFLICT cycles in k_cnt_gemm1 (512B row
// stride = same bank for all nodes). Everything else identical to r16/r21.
// Assumes N <= 131072.

#define F_IN 128
#define XTP 132          // padded row stride (floats); 132 % 32 = 4
#define H1 16
#define C_OUT 2
#define SBS 1024         // nodes per super-bucket
#define LOG_SBS 10
#define NSB_MAX 128
#define SRC_MASK 0x3FFFFF   // 22-bit src
#define CH1 4096         // edges per chunk (782 chunks)
#define SLICE 128        // nodes per place-slice
#define NSLICE (SBS / SLICE)   // 8
#define PCAP 5632        // staged edges per slice (expected ~4096, +24 sigma)

typedef int ix4 __attribute__((ext_vector_type(4)));

__device__ __forceinline__ float bflo(unsigned u) { return __uint_as_float(u << 16); }
__device__ __forceinline__ float bfhi(unsigned u) { return __uint_as_float(u & 0xFFFF0000u); }

// ---- fused: [0, nblk) = per-chunk SB histogram; [nblk, ..) = layer-1 GEMM ----
__global__ __launch_bounds__(512) void k_cnt_gemm1(
    const int* __restrict__ dst0, int* __restrict__ cntm,
    const float* __restrict__ x, const float* __restrict__ W1,
    __hip_bfloat16* __restrict__ h1b,
    int E, int NSB, int nblk, int N) {
    __shared__ int sc[NSB_MAX];
    __shared__ float w[F_IN * H1];     // 8 KB
    __shared__ float xt[32 * XTP];     // 16.9 KB (padded rows)
    int t = threadIdx.x;
    if (blockIdx.x < (unsigned)nblk) {
        // ---- cnt ----
        if (t < NSB_MAX) sc[t] = 0;
        __syncthreads();
        int e0 = blockIdx.x * CH1, e1 = min(e0 + CH1, E);
        int n4 = (e1 - e0) >> 2;
        const ix4* d4 = (const ix4*)(dst0 + e0);
        for (int i = t; i < n4; i += 512) {
            ix4 d = __builtin_nontemporal_load(&d4[i]);
            atomicAdd(&sc[((unsigned)d.x) >> LOG_SBS], 1);
            atomicAdd(&sc[((unsigned)d.y) >> LOG_SBS], 1);
            atomicAdd(&sc[((unsigned)d.z) >> LOG_SBS], 1);
            atomicAdd(&sc[((unsigned)d.w) >> LOG_SBS], 1);
        }
        for (int e = e0 + n4 * 4 + t; e < e1; e += 512)
            atomicAdd(&sc[((unsigned)dst0[e]) >> LOG_SBS], 1);
        __syncthreads();
        for (int b = t; b < NSB; b += 512)
            cntm[(size_t)b * nblk + blockIdx.x] = sc[b];
    } else {
        // ---- gemm1 (UNSCALED h1): 32 nodes, 512 threads, padded tile ----
        int node0 = (blockIdx.x - nblk) * 32;
        const float4* W14 = (const float4*)W1;
        float4* w4 = (float4*)w;
        for (int i = t; i < F_IN * H1 / 4; i += 512) w4[i] = W14[i];
        const float4* x4 = (const float4*)x;
        for (int i = t; i < 32 * 32; i += 512) {
            int r = i >> 5, c = i & 31;
            int node = node0 + r;
            float4 v = (node < N) ? x4[(size_t)node * 32 + c]
                                  : make_float4(0.f, 0.f, 0.f, 0.f);
            *((float4*)(xt + r * XTP + c * 4)) = v;
        }
        __syncthreads();
        int nsub = t >> 4, f = t & 15;          // 32 nodes x 16 feats
        int node = node0 + nsub;
        if (node < N) {
            const float4* xr = (const float4*)(xt + nsub * XTP);
            float a0 = 0.f, a1 = 0.f, a2 = 0.f, a3 = 0.f;
            #pragma unroll
            for (int k4 = 0; k4 < 8; ++k4) {     // 8 float4 per chunk of 32
                float4 v0 = xr[k4];
                float4 v1 = xr[8 + k4];
                float4 v2 = xr[16 + k4];
                float4 v3 = xr[24 + k4];
                int k0 = k4 * 4;
                a0 = fmaf(v0.x, w[(k0+0)*H1+f], a0);
                a0 = fmaf(v0.y, w[(k0+1)*H1+f], a0);
                a0 = fmaf(v0.z, w[(k0+2)*H1+f], a0);
                a0 = fmaf(v0.w, w[(k0+3)*H1+f], a0);
                a1 = fmaf(v1.x, w[(32+k0+0)*H1+f], a1);
                a1 = fmaf(v1.y, w[(32+k0+1)*H1+f], a1);
                a1 = fmaf(v1.z, w[(32+k0+2)*H1+f], a1);
                a1 = fmaf(v1.w, w[(32+k0+3)*H1+f], a1);
                a2 = fmaf(v2.x, w[(64+k0+0)*H1+f], a2);
                a2 = fmaf(v2.y, w[(64+k0+1)*H1+f], a2);
                a2 = fmaf(v2.z, w[(64+k0+2)*H1+f], a2);
                a2 = fmaf(v2.w, w[(64+k0+3)*H1+f], a2);
                a3 = fmaf(v3.x, w[(96+k0+0)*H1+f], a3);
                a3 = fmaf(v3.y, w[(96+k0+1)*H1+f], a3);
                a3 = fmaf(v3.z, w[(96+k0+2)*H1+f], a3);
                a3 = fmaf(v3.w, w[(96+k0+3)*H1+f], a3);
            }
            h1b[(size_t)node * H1 + f] = __float2bfloat16((a0 + a1) + (a2 + a3));
        }
    }
}

// ---- pass 0b: per-SB exclusive scan over chunks (block per SB) + totals ----
__global__ __launch_bounds__(1024) void k_cscan(
    int* __restrict__ cntm, int* __restrict__ tot, int* __restrict__ rp,
    int NSB, int nblk, int E) {
    __shared__ int s[1024];
    int b = blockIdx.x, t = threadIdx.x;
    int* row = cntm + (size_t)b * nblk;
    int own = (t < nblk) ? row[t] : 0;
    s[t] = own;
    __syncthreads();
    for (int off = 1; off < 1024; off <<= 1) {
        int v = (t >= off) ? s[t - off] : 0;
        __syncthreads();
        s[t] += v;
        __syncthreads();
    }
    if (t < nblk) row[t] = s[t] - own;      // exclusive prefix
    if (t == 0) tot[b] = s[1023];           // SB total (zero-padded tail)
    if (b == 0 && t == 0) rp[NSB * SBS] = E;
}

// ---- pass 1: scatter (src | dst_local<<22) at precomputed offsets ----
__global__ __launch_bounds__(512) void k_scat1(
    const int* __restrict__ src0, const int* __restrict__ dst0,
    const int* __restrict__ cntm, unsigned* __restrict__ packed1,
    int E, int NSB, int nblk, int CAP) {
    __shared__ int lcur[NSB_MAX];
    int t = threadIdx.x, blk = blockIdx.x;
    for (int b = t; b < NSB; b += 512)
        lcur[b] = b * CAP + cntm[(size_t)b * nblk + blk];
    __syncthreads();
    int e0 = blk * CH1, e1 = min(e0 + CH1, E);
    int n4 = (e1 - e0) >> 2;
    const ix4* d4 = (const ix4*)(dst0 + e0);
    const ix4* s4 = (const ix4*)(src0 + e0);
    for (int i = t; i < n4; i += 512) {
        ix4 d = __builtin_nontemporal_load(&d4[i]);
        ix4 s = __builtin_nontemporal_load(&s4[i]);
        {
            unsigned dd = (unsigned)d.x;
            int pos = atomicAdd(&lcur[dd >> LOG_SBS], 1);
            packed1[pos] = (unsigned)s.x | ((dd & (SBS - 1)) << 22);
        }
        {
            unsigned dd = (unsigned)d.y;
            int pos = atomicAdd(&lcur[dd >> LOG_SBS], 1);
            packed1[pos] = (unsigned)s.y | ((dd & (SBS - 1)) << 22);
        }
        {
            unsigned dd = (unsigned)d.z;
            int pos = atomicAdd(&lcur[dd >> LOG_SBS], 1);
            packed1[pos] = (unsigned)s.z | ((dd & (SBS - 1)) << 22);
        }
        {
            unsigned dd = (unsigned)d.w;
            int pos = atomicAdd(&lcur[dd >> LOG_SBS], 1);
            packed1[pos] = (unsigned)s.w | ((dd & (SBS - 1)) << 22);
        }
    }
    for (int e = e0 + n4 * 4 + t; e < e1; e += 512) {
        unsigned dd = (unsigned)dst0[e];
        int pos = atomicAdd(&lcur[dd >> LOG_SBS], 1);
        packed1[pos] = (unsigned)src0[e] | ((dd & (SBS - 1)) << 22);
    }
}

// ---- pass 2a: per-SB histogram + scan -> rp, dinv; epilogue: h1b *= dinv ----
__global__ __launch_bounds__(1024) void k_hist(
    const unsigned* __restrict__ packed1, const int* __restrict__ tot,
    int* __restrict__ rp, float* __restrict__ dinv,
    __hip_bfloat16* __restrict__ h1b, int N, int NSB, int CAP) {
    __shared__ int cnt[SBS];
    __shared__ int s2[SBS];
    __shared__ int sbase[NSB_MAX];
    int b = blockIdx.x, t = threadIdx.x;
    if (t < NSB_MAX) sbase[t] = (t < NSB) ? tot[t] : 0;
    cnt[t] = 0;
    __syncthreads();
    if (t == 0) {
        int run = 0;
        #pragma unroll 4
        for (int i = 0; i < NSB_MAX; ++i) { int c = sbase[i]; sbase[i] = run; run += c; }
    }
    __syncthreads();
    int cntb = tot[b];
    int e0 = b * CAP, e1 = e0 + cntb;
    int obase = sbase[b];
    int n4 = cntb >> 2;
    const ix4* p4 = (const ix4*)(packed1 + e0);
    for (int i = t; i < n4; i += 1024) {
        ix4 p = p4[i];
        atomicAdd(&cnt[((unsigned)p.x) >> 22], 1);
        atomicAdd(&cnt[((unsigned)p.y) >> 22], 1);
        atomicAdd(&cnt[((unsigned)p.z) >> 22], 1);
        atomicAdd(&cnt[((unsigned)p.w) >> 22], 1);
    }
    for (int e = e0 + n4 * 4 + t; e < e1; e += 1024)
        atomicAdd(&cnt[packed1[e] >> 22], 1);
    __syncthreads();
    int c = cnt[t];
    s2[t] = c;
    __syncthreads();
    for (int off = 1; off < 1024; off <<= 1) {
        int v = (t >= off) ? s2[t - off] : 0;
        __syncthreads();
        s2[t] += v;
        __syncthreads();
    }
    int ep = s2[t] - c;                 // exclusive prefix within SB
    int node = (b << LOG_SBS) + t;
    rp[node] = obase + ep;              // defined for ALL SB nodes
    if (node < N) {
        float dv = rsqrtf((float)(c + 1));   // +1 self-loop
        dinv[node] = dv;
        uint4* hrow = (uint4*)(h1b + (size_t)node * H1);
        uint4 s0 = hrow[0], s1 = hrow[1];
        unsigned r0[8];
        float v0, v1;
        #define SCALE_PACK(word, outi) \
            v0 = bflo(word) * dv; v1 = bfhi(word) * dv; \
            r0[outi] = (unsigned)__bfloat16_as_ushort(__float2bfloat16(v0)) | \
                       ((unsigned)__bfloat16_as_ushort(__float2bfloat16(v1)) << 16);
        SCALE_PACK(s0.x, 0) SCALE_PACK(s0.y, 1) SCALE_PACK(s0.z, 2) SCALE_PACK(s0.w, 3)
        SCALE_PACK(s1.x, 4) SCALE_PACK(s1.y, 5) SCALE_PACK(s1.z, 6) SCALE_PACK(s1.w, 7)
        #undef SCALE_PACK
        hrow[0] = make_uint4(r0[0], r0[1], r0[2], r0[3]);
        hrow[1] = make_uint4(r0[4], r0[5], r0[6], r0[7]);
    }
}

// ---- pass 2b+agg1: placement + in-block layer-1 aggregation ----
__global__ __launch_bounds__(512) void k_place_agg1(
    const unsigned* __restrict__ packed1, const int* __restrict__ tot,
    const int* __restrict__ rp, int* __restrict__ packed2,
    const __hip_bfloat16* __restrict__ h1b, const float* __restrict__ dinv,
    const float* __restrict__ b1, const float* __restrict__ W2,
    float* __restrict__ h2s,
    int N, int NSB, int PADB, int CAP) {
    __shared__ int cur[SLICE];
    __shared__ int lbuf[PCAP];
    int bid = blockIdx.x;
    int s = bid / PADB, b = bid - s * PADB;
    if (b >= NSB) return;
    int t = threadIdx.x;
    int node0 = (b << LOG_SBS) + s * SLICE;
    int g0 = rp[node0];
    if (t < SLICE) cur[t] = rp[node0 + t] - g0;
    int slice_len = rp[node0 + SLICE] - g0;
    __syncthreads();
    int cntb = tot[b];
    int e0 = b * CAP, e1 = e0 + cntb;
    int n4 = cntb >> 2;
    const ix4* p4 = (const ix4*)(packed1 + e0);
    for (int i = t; i < n4; i += 512) {
        ix4 p = p4[i];
        {
            unsigned nd = ((unsigned)p.x) >> 22;
            if ((nd >> 7) == (unsigned)s) {
                int pos = atomicAdd(&cur[nd & (SLICE - 1)], 1);
                if (pos < PCAP) lbuf[pos] = p.x & SRC_MASK;
            }
        }
        {
            unsigned nd = ((unsigned)p.y) >> 22;
            if ((nd >> 7) == (unsigned)s) {
                int pos = atomicAdd(&cur[nd & (SLICE - 1)], 1);
                if (pos < PCAP) lbuf[pos] = p.y & SRC_MASK;
            }
        }
        {
            unsigned nd = ((unsigned)p.z) >> 22;
            if ((nd >> 7) == (unsigned)s) {
                int pos = atomicAdd(&cur[nd & (SLICE - 1)], 1);
                if (pos < PCAP) lbuf[pos] = p.z & SRC_MASK;
            }
        }
        {
            unsigned nd = ((unsigned)p.w) >> 22;
            if ((nd >> 7) == (unsigned)s) {
                int pos = atomicAdd(&cur[nd & (SLICE - 1)], 1);
                if (pos < PCAP) lbuf[pos] = p.w & SRC_MASK;
            }
        }
    }
    for (int e = e0 + n4 * 4 + t; e < e1; e += 512) {
        unsigned p = packed1[e];
        unsigned nd = p >> 22;
        if ((nd >> 7) == (unsigned)s) {
            int pos = atomicAdd(&cur[nd & (SLICE - 1)], 1);
            if (pos < PCAP) lbuf[pos] = (int)(p & SRC_MASK);
        }
    }
    __syncthreads();
    // write packed2 for agg2 (sequential full-line writes)
    int lim = min(slice_len, PCAP);
    for (int i = t; i < lim; i += 512)
        packed2[g0 + i] = lbuf[i];
    // ---- fused layer-1 aggregation: 4 threads/node from LDS indices ----
    int g = t >> 2, q = t & 3;          // g in [0,128)
    int node = node0 + g;
    if (node < N) {
        const uint2* hv = (const uint2*)h1b;   // 8B chunks; row = 4 chunks
        float a[4];
        uint2 sv = hv[(size_t)node * 4 + q];   // self (pre-scaled)
        a[0] = bflo(sv.x); a[1] = bfhi(sv.x); a[2] = bflo(sv.y); a[3] = bfhi(sv.y);
        int lb = rp[node] - g0;
        int le = min(rp[node + 1] - g0, PCAP);
        for (; lb + 8 <= le; lb += 8) {
            int p[8];
            #pragma unroll
            for (int u = 0; u < 8; ++u) p[u] = lbuf[lb + u];
            uint2 v[8];
            #pragma unroll
            for (int u = 0; u < 8; ++u) v[u] = hv[(size_t)p[u] * 4 + q];
            #pragma unroll
            for (int u = 0; u < 8; ++u) {
                a[0] += bflo(v[u].x); a[1] += bfhi(v[u].x);
                a[2] += bflo(v[u].y); a[3] += bfhi(v[u].y);
            }
        }
        for (; lb < le; ++lb) {
            uint2 v = hv[(size_t)lbuf[lb] * 4 + q];
            a[0] += bflo(v.x); a[1] += bfhi(v.x); a[2] += bflo(v.y); a[3] += bfhi(v.y);
        }
        float dv = dinv[node];
        float c0 = 0.f, c1 = 0.f;
        #pragma unroll
        for (int j = 0; j < 4; ++j) {
            int f = q * 4 + j;
            float vv = fmaxf(fmaf(a[j], dv, b1[f]), 0.f);
            c0 = fmaf(vv, W2[f * C_OUT + 0], c0);
            c1 = fmaf(vv, W2[f * C_OUT + 1], c1);
        }
        c0 += __shfl_xor(c0, 1);
        c1 += __shfl_xor(c1, 1);
        c0 += __shfl_xor(c0, 2);
        c1 += __shfl_xor(c1, 2);
        if (q == 0)
            ((float2*)h2s)[node] = make_float2(c0 * dv, c1 * dv);
    }
}

// ---- layer 2 aggregate + log_softmax, 2 threads per node ----
__global__ __launch_bounds__(256) void k_agg2(
    const int* __restrict__ packed2, const int* __restrict__ rp,
    const float* __restrict__ h2s, const float* __restrict__ dinv,
    const float* __restrict__ b2, float* __restrict__ out, int N) {
    int tid = blockIdx.x * 256 + threadIdx.x;
    int n = tid >> 1, q = tid & 1;
    if (n >= N) return;
    float a = h2s[2 * (size_t)n + q];   // self-loop
    int e = rp[n], e1 = rp[n + 1];
    for (; e + 8 <= e1; e += 8) {
        int p[8];
        #pragma unroll
        for (int u = 0; u < 8; ++u) p[u] = packed2[e + u];
        float v[8];
        #pragma unroll
        for (int u = 0; u < 8; ++u) v[u] = h2s[2 * (size_t)p[u] + q];
        #pragma unroll
        for (int u = 0; u < 8; ++u) a += v[u];
    }
    for (; e < e1; ++e) a += h2s[2 * (size_t)packed2[e] + q];
    float dv = dinv[n];
    a = fmaf(a, dv, b2[q]);
    float other = __shfl_xor(a, 1);
    if (q == 0) {
        float a0 = a, a1 = other;
        float m = fmaxf(a0, a1);
        float lse = m + logf(expf(a0 - m) + expf(a1 - m));
        ((float2*)out)[n] = make_float2(a0 - lse, a1 - lse);
    }
}

extern "C" void kernel_launch(void* const* d_in, const int* in_sizes, int n_in,
                              void* d_out, int out_size, void* d_ws, size_t ws_size,
                              hipStream_t stream) {
    const float* x  = (const float*)d_in[0];
    const int* ei   = (const int*)d_in[1];
    const float* W1 = (const float*)d_in[2];
    const float* b1 = (const float*)d_in[3];
    const float* W2 = (const float*)d_in[4];
    const float* b2 = (const float*)d_in[5];
    float* out = (float*)d_out;

    const int N = in_sizes[0] / F_IN;     // 100000 (assumed <= 131072)
    const int E = in_sizes[1] / 2;        // 3200000
    const int* src0 = ei;
    const int* dst0 = ei + E;

    const int NSB = (N + SBS - 1) >> LOG_SBS;    // 98
    const int nblk = (E + CH1 - 1) / CH1;        // 782 (must be <= 1024 for cscan)
    const int PADB = (NSB + 7) & ~7;             // 104 (x8 XCD-stable mapping)
    int expSB = (int)(((long long)E << LOG_SBS) / N);
    int CAP = (expSB + expSB / 8 + 2048 + 15) & ~15;

    // workspace layout (float units), 16B-aligned chunks
    size_t off = 0;
    float* wsf = (float*)d_ws;
    auto take = [&](size_t nf) { float* p = wsf + off; off += (nf + 3) & ~(size_t)3; return p; };
    float* dinv    = take(N);
    __hip_bfloat16* h1b = (__hip_bfloat16*)take((size_t)N * H1 / 2);
    float* h2s     = take((size_t)N * C_OUT);
    unsigned* packed1 = (unsigned*)take((size_t)NSB * CAP);
    int*   packed2 = (int*)take(E);
    int*   cntm    = (int*)take((size_t)NSB * nblk);
    int*   tot     = (int*)take(NSB_MAX);
    int*   rp      = (int*)take((size_t)NSB * SBS + 1);

    int nbGemm = (N + 31) / 32;
    k_cnt_gemm1<<<nblk + nbGemm, 512, 0, stream>>>(dst0, cntm, x, W1, h1b, E, NSB, nblk, N);
    k_cscan<<<NSB, 1024, 0, stream>>>(cntm, tot, rp, NSB, nblk, E);
    k_scat1<<<nblk, 512, 0, stream>>>(src0, dst0, cntm, packed1, E, NSB, nblk, CAP);
    k_hist<<<NSB, 1024, 0, stream>>>(packed1, tot, rp, dinv, h1b, N, NSB, CAP);
    k_place_agg1<<<NSLICE * PADB, 512, 0, stream>>>(packed1, tot, rp, packed2,
                                                    h1b, dinv, b1, W2, h2s, N, NSB, PADB, CAP);
    k_agg2<<<(2 * N + 255) / 256, 256, 0, stream>>>(packed2, rp, h2s, dinv, b2, out, N);
}